// Round 3
// baseline (159.049 us; speedup 1.0000x reference)
//
#include <hip/hip_runtime.h>

#define NN 4096
#define NC 10
#define NW 64           // 64-bit words per adjacency row
typedef unsigned long long u64;

#define S1F 0.73105857863000489f   // sigmoid(1.0)

// ---------------- kernel 1: pack adjacency rows into bitmasks + degrees ----
__global__ __launch_bounds__(256) void pack_bits_kernel(
    const int* __restrict__ adj, u64* __restrict__ bits, int* __restrict__ deg) {
  int p = blockIdx.x;            // one block per row
  int tid = threadIdx.x;         // 256 threads = 4 waves
  int wv = tid >> 6, lane = tid & 63;
  const int* row = adj + (size_t)p * NN;
  int cnt = 0;
  for (int w = wv; w < NW; w += 4) {
    int a = row[(w << 6) + lane];
    u64 b = __ballot(a != 0);
    if (lane == 0) bits[(size_t)p * NW + w] = b;
    cnt += (a != 0) ? 1 : 0;
  }
  __shared__ int red[256];
  red[tid] = cnt;
  __syncthreads();
  for (int s = 128; s > 0; s >>= 1) {
    if (tid < s) red[tid] += red[tid + s];
    __syncthreads();
  }
  if (tid == 0) deg[p] = red[0];
}

// ---------------- kernel 2: per-node CE + pos + per-class masked counts ----
__global__ __launch_bounds__(256) void node_kernel(
    const float* __restrict__ preds, const int* __restrict__ labels,
    const int* __restrict__ mask, float* __restrict__ pos,
    int* __restrict__ Ncnt, float* __restrict__ ceAcc) {
  int n = blockIdx.x * blockDim.x + threadIdx.x;
  float ce = 0.f;
  if (n < NN) {
    int l = labels[n];
    float r[NC];
    float mx = -1e30f, rl = 0.f;
#pragma unroll
    for (int c = 0; c < NC; c++) {
      float v = preds[n * NC + c];
      r[c] = v;
      if (c == l) rl = v;          // avoid runtime-indexed register array
      mx = fmaxf(mx, v);
    }
    float s = 0.f;
#pragma unroll
    for (int c = 0; c < NC; c++) s += expf(r[c] - mx);
    float lse = mx + logf(s);
    pos[n] = rl;
    ce = lse - rl;                 // -log p(label)
    if (mask[n] != 0) atomicAdd(&Ncnt[l], 1);
  }
  __shared__ float red[256];
  red[threadIdx.x] = ce;
  __syncthreads();
  for (int s = 128; s > 0; s >>= 1) {
    if (threadIdx.x < s) red[threadIdx.x] += red[threadIdx.x + s];
    __syncthreads();
  }
  if (threadIdx.x == 0) atomicAdd(ceAcc, red[0]);
}

// ---------------- kernel 3: deterministic mask compaction (1 block) --------
__global__ __launch_bounds__(256) void compact_kernel(
    const int* __restrict__ mask, int* __restrict__ list, int* __restrict__ Mcount) {
  __shared__ int cnt[256];
  int tid = threadIdx.x;
  int base = tid * 16;
  int c = 0;
  for (int i = 0; i < 16; i++) c += (mask[base + i] != 0) ? 1 : 0;
  cnt[tid] = c;
  __syncthreads();
  for (int s = 1; s < 256; s <<= 1) {   // Hillis-Steele inclusive scan
    int v = (tid >= s) ? cnt[tid - s] : 0;
    __syncthreads();
    cnt[tid] += v;
    __syncthreads();
  }
  int off = cnt[tid] - c;               // exclusive offset
  for (int i = 0; i < 16; i++) {
    int idx = base + i;
    if (mask[idx] != 0) list[off++] = idx;
  }
  if (tid == 255) *Mcount = cnt[255];
}

// ---------------- kernel 4: masked-pair popcount + class-pair bins ---------
__global__ __launch_bounds__(256) void pair_kernel(
    const u64* __restrict__ bits, const int* __restrict__ deg,
    const float* __restrict__ pos, const float* __restrict__ preds,
    const int* __restrict__ labels, const int* __restrict__ list,
    const int* __restrict__ Mcount,
    float* __restrict__ gSsub, float* __restrict__ gSint, float* __restrict__ gT) {
  __shared__ u64 BP[64][NW + 1];        // +1 word pad vs bank conflicts
  __shared__ u64 BQ[64][NW + 1];
  __shared__ float predQ[64][NC];
  __shared__ int nodeP[64], nodeQ[64], labP[64], labQ[64], degP[64];
  __shared__ float posP[64];
  __shared__ float binS[100], binI[100], binT[100];

  int M = *Mcount;
  int ntp = (M + 63) >> 6;
  int ntiles = ntp * ntp;
  int tid = threadIdx.x;

  for (int tile = blockIdx.x; tile < ntiles; tile += gridDim.x) {
    int tp = tile / ntp;
    int tq = tile - tp * ntp;

    // phase 1: row metadata + bin init
    if (tid < 64) {
      int mp = (tp << 6) + tid;
      int pg = (mp < M) ? list[mp] : -1;
      nodeP[tid] = pg;
      labP[tid]  = (pg >= 0) ? labels[pg] : -1;
      degP[tid]  = (pg >= 0) ? deg[pg] : 0;
      posP[tid]  = (pg >= 0) ? pos[pg] : 0.f;
    } else if (tid < 128) {
      int r = tid - 64;
      int mq = (tq << 6) + r;
      int qg = (mq < M) ? list[mq] : -1;
      nodeQ[r] = qg;
      labQ[r]  = (qg >= 0) ? labels[qg] : -1;
    }
    for (int i = tid; i < 100; i += 256) { binS[i] = 0.f; binI[i] = 0.f; binT[i] = 0.f; }
    __syncthreads();

    // phase 2: stage bit rows + Q-tile preds
    for (int idx = tid; idx < 64 * NW; idx += 256) {
      int r = idx >> 6, w = idx & 63;
      int pg = nodeP[r], qg = nodeQ[r];
      BP[r][w] = (pg >= 0) ? bits[(size_t)pg * NW + w] : 0ULL;
      BQ[r][w] = (qg >= 0) ? bits[(size_t)qg * NW + w] : 0ULL;
    }
    for (int idx = tid; idx < 64 * NC; idx += 256) {
      int r = idx / NC, c = idx - r * NC;
      int qg = nodeQ[r];
      predQ[r][c] = (qg >= 0) ? preds[qg * NC + c] : 0.f;
    }
    __syncthreads();

    // phase 3: 4x4 pair register tile per thread
    int tx = tid & 15, ty = tid >> 4;
    int acc[4][4];
#pragma unroll
    for (int i = 0; i < 4; i++)
#pragma unroll
      for (int j = 0; j < 4; j++) acc[i][j] = 0;

#pragma unroll 4
    for (int w = 0; w < NW; w++) {
      u64 rp[4], rq[4];
#pragma unroll
      for (int i = 0; i < 4; i++) rp[i] = BP[(ty << 2) + i][w];
#pragma unroll
      for (int j = 0; j < 4; j++) rq[j] = BQ[(tx << 2) + j][w];
#pragma unroll
      for (int i = 0; i < 4; i++)
#pragma unroll
        for (int j = 0; j < 4; j++)
          acc[i][j] += (int)__popcll(rp[i] & rq[j]);
    }

#pragma unroll
    for (int i = 0; i < 4; i++) {
      int pl = (ty << 2) + i;
      int li = labP[pl];
      if (li < 0) continue;
#pragma unroll
      for (int j = 0; j < 4; j++) {
        int ql = (tx << 2) + j;
        int lj = labQ[ql];
        if (lj < 0) continue;
        int inter = acc[i][j];
        int qg = nodeQ[ql];
        int wq = qg >> 6;
        u64 mbit = 1ULL << (qg & 63);
        int apq = (BP[pl][wq] & mbit) ? 1 : 0;
        int aqq = (BQ[ql][wq] & mbit) ? 1 : 0;
        // sub_cnt = deg(p) - inter - adj[p,q]*(1-adj[q,q])
        int sub = degP[pl] - inter - (apq & (1 - aqq));
        int bin = li * NC + lj;
        atomicAdd(&binS[bin], (float)sub);
        atomicAdd(&binI[bin], (float)inter);
        if (li != lj) {
          float E = expf(predQ[ql][li] - posP[pl]);     // exp(-(pos_p - neg_pq))
          float x = (1.f + S1F * (float)sub) / (1.f + S1F * (float)inter);
          float v = 1.f / (1.f + expf(x));              // 1 - sigmoid(x)
          atomicAdd(&binT[bin], E * v);
        }
      }
    }
    __syncthreads();

    // phase 4: flush bins
    for (int i = tid; i < 100; i += 256) {
      if (binS[i] != 0.f) atomicAdd(&gSsub[i], binS[i]);
      if (binI[i] != 0.f) atomicAdd(&gSint[i], binI[i]);
      if (binT[i] != 0.f) atomicAdd(&gT[i],   binT[i]);
    }
    __syncthreads();   // protect LDS before next tile's staging
  }
}

// ---------------- kernel 5: final gate + reduce ----------------------------
__global__ __launch_bounds__(128) void finalize_kernel(
    const float* __restrict__ gSsub, const float* __restrict__ gSint,
    const float* __restrict__ gT, const int* __restrict__ Ncnt,
    const float* __restrict__ ceAcc, float* __restrict__ out) {
  __shared__ float red[128];
  int tid = threadIdx.x;
  float val = 0.f;
  if (tid < 100) {
    int i = tid / NC, j = tid - (tid / NC) * NC;
    if (i != j && gSsub[tid] > 0.f && gSint[tid] > 0.f) {
      float Ni = fmaxf((float)Ncnt[i], 1.f);
      float Nj = fmaxf((float)Ncnt[j], 1.f);
      val = gT[tid] / (Ni * Nj);
    }
  }
  red[tid] = val;
  __syncthreads();
  for (int s = 64; s > 0; s >>= 1) {
    if (tid < s) red[tid] += red[tid + s];
    __syncthreads();
  }
  if (tid == 0) out[0] = ceAcc[0] / (float)NN + 0.001f * red[0];
}

// ---------------- launch ---------------------------------------------------
extern "C" void kernel_launch(void* const* d_in, const int* in_sizes, int n_in,
                              void* d_out, int out_size, void* d_ws, size_t ws_size,
                              hipStream_t stream) {
  const float* preds  = (const float*)d_in[0];
  const int*   labels = (const int*)d_in[1];
  const int*   mask   = (const int*)d_in[2];
  const int*   adj    = (const int*)d_in[3];

  char* ws = (char*)d_ws;
  // workspace layout (bytes):
  //   [0, 2097152)        bits   (4096 rows x 64 u64)
  //   [2097152, +16384)   deg    (int[4096])
  //   [2113536, +16384)   pos    (float[4096])
  //   [2129920, +16384)   list   (int[4096])
  //   [2146304, +1536)    accumulators (zeroed each call)
  u64*   bits  = (u64*)(ws + 0);
  int*   deg   = (int*)(ws + 2097152);
  float* pos   = (float*)(ws + 2113536);
  int*   list  = (int*)(ws + 2129920);
  char*  accb  = ws + 2146304;
  float* ceAcc = (float*)(accb + 0);
  int*   Mcnt  = (int*)(accb + 8);
  int*   Ncnt  = (int*)(accb + 16);      // 10 ints
  float* gSsub = (float*)(accb + 64);    // 100 floats
  float* gSint = (float*)(accb + 512);   // 100 floats
  float* gT    = (float*)(accb + 1024);  // 100 floats

  hipMemsetAsync(accb, 0, 1536, stream);

  hipLaunchKernelGGL(pack_bits_kernel, dim3(NN), dim3(256), 0, stream, adj, bits, deg);
  hipLaunchKernelGGL(node_kernel, dim3(NN / 256), dim3(256), 0, stream,
                     preds, labels, mask, pos, Ncnt, ceAcc);
  hipLaunchKernelGGL(compact_kernel, dim3(1), dim3(256), 0, stream, mask, list, Mcnt);
  hipLaunchKernelGGL(pair_kernel, dim3(1024), dim3(256), 0, stream,
                     bits, deg, pos, preds, labels, list, Mcnt, gSsub, gSint, gT);
  hipLaunchKernelGGL(finalize_kernel, dim3(1), dim3(128), 0, stream,
                     gSsub, gSint, gT, Ncnt, ceAcc, (float*)d_out);
}

// Round 4
// 112.441 us; speedup vs baseline: 1.4145x; 1.4145x over previous
//
#include <hip/hip_runtime.h>

#define NN 4096
#define NC 10
#define NW 64           // 64-bit words per adjacency row
#define CH 32           // words per LDS chunk (2 chunks cover a row)
typedef unsigned long long u64;

#define S1F 0.73105857863000489f   // sigmoid(1.0)

// ---------------- kernel 1: pack adjacency rows into bitmasks + degrees ----
__global__ __launch_bounds__(256) void pack_bits_kernel(
    const int* __restrict__ adj, u64* __restrict__ bits, int* __restrict__ deg) {
  int p = blockIdx.x;            // one block per row
  int tid = threadIdx.x;         // 256 threads = 4 waves
  int wv = tid >> 6, lane = tid & 63;
  const int* row = adj + (size_t)p * NN;
  int cnt = 0;
  for (int w = wv; w < NW; w += 4) {
    int a = row[(w << 6) + lane];
    u64 b = __ballot(a != 0);
    if (lane == 0) bits[(size_t)p * NW + w] = b;
    cnt += (a != 0) ? 1 : 0;
  }
  __shared__ int red[256];
  red[tid] = cnt;
  __syncthreads();
  for (int s = 128; s > 0; s >>= 1) {
    if (tid < s) red[tid] += red[tid + s];
    __syncthreads();
  }
  if (tid == 0) deg[p] = red[0];
}

// ---------------- kernel 2: per-node CE + pos + per-class masked counts ----
__global__ __launch_bounds__(256) void node_kernel(
    const float* __restrict__ preds, const int* __restrict__ labels,
    const int* __restrict__ mask, float* __restrict__ pos,
    int* __restrict__ Ncnt, float* __restrict__ ceAcc) {
  int n = blockIdx.x * blockDim.x + threadIdx.x;
  float ce = 0.f;
  if (n < NN) {
    int l = labels[n];
    float r[NC];
    float mx = -1e30f, rl = 0.f;
#pragma unroll
    for (int c = 0; c < NC; c++) {
      float v = preds[n * NC + c];
      r[c] = v;
      if (c == l) rl = v;          // avoid runtime-indexed register array
      mx = fmaxf(mx, v);
    }
    float s = 0.f;
#pragma unroll
    for (int c = 0; c < NC; c++) s += expf(r[c] - mx);
    float lse = mx + logf(s);
    pos[n] = rl;
    ce = lse - rl;                 // -log p(label)
    if (mask[n] != 0) atomicAdd(&Ncnt[l], 1);
  }
  __shared__ float red[256];
  red[threadIdx.x] = ce;
  __syncthreads();
  for (int s = 128; s > 0; s >>= 1) {
    if (threadIdx.x < s) red[threadIdx.x] += red[threadIdx.x + s];
    __syncthreads();
  }
  if (threadIdx.x == 0) atomicAdd(ceAcc, red[0]);
}

// ---------------- kernel 3: deterministic mask compaction (1 block) --------
__global__ __launch_bounds__(256) void compact_kernel(
    const int* __restrict__ mask, int* __restrict__ list, int* __restrict__ Mcount) {
  __shared__ int cnt[256];
  int tid = threadIdx.x;
  int base = tid * 16;
  int c = 0;
  for (int i = 0; i < 16; i++) c += (mask[base + i] != 0) ? 1 : 0;
  cnt[tid] = c;
  __syncthreads();
  for (int s = 1; s < 256; s <<= 1) {   // Hillis-Steele inclusive scan
    int v = (tid >= s) ? cnt[tid - s] : 0;
    __syncthreads();
    cnt[tid] += v;
    __syncthreads();
  }
  int off = cnt[tid] - c;               // exclusive offset
  for (int i = 0; i < 16; i++) {
    int idx = base + i;
    if (mask[idx] != 0) list[off++] = idx;
  }
  if (tid == 255) *Mcount = cnt[255];
}

// ---------------- kernel 4: symmetric masked-pair popcount -----------------
// Tiles (tp,tq) with tp<=tq; each unordered pair computed once, both
// orientations emitted. LDS bit tiles XOR-swizzled (word ^= ((row>>2)&7)<<1,
// 16B-granular) so ds_read_b64 is bank-conflict-free. Gate sums replaced by
// exact OR flags (counts are >=0, so sum>0 <=> exists>0).
__global__ __launch_bounds__(256, 4) void pair_kernel(
    const u64* __restrict__ bits, const int* __restrict__ deg,
    const float* __restrict__ pos, const float* __restrict__ preds,
    const int* __restrict__ labels, const int* __restrict__ list,
    const int* __restrict__ Mcount,
    float* __restrict__ gT, int* __restrict__ gS, int* __restrict__ gI) {
  __shared__ u64 BPs[64][CH];        // 16 KB, physical col = logical ^ swz(row)
  __shared__ u64 BQs[64][CH];        // 16 KB
  __shared__ float posP[64], posQ[64];
  __shared__ int nodeP[64], nodeQ[64], labP[64], labQ[64];
  __shared__ int degP[64], degQ[64], selfP[64], selfQ[64];
  __shared__ float binT[100];
  __shared__ int binS[100], binI[100];

  int M = *Mcount;
  int ntp = (M + 63) >> 6;
  int ntiles = (ntp * (ntp + 1)) >> 1;
  int tid = threadIdx.x;
  int tx = tid & 15, ty = tid >> 4;
  int swzP = (ty & 7) << 1;          // ((4ty+i)>>2)&7 == ty&7 for i<4
  int swzQ = (tx & 7) << 1;

  for (int t = blockIdx.x; t < ntiles; t += gridDim.x) {
    int tp = 0, rem = t;             // linear -> (tp,tq), tp<=tq (uniform)
    while (rem >= ntp - tp) { rem -= ntp - tp; tp++; }
    int tq = tp + rem;
    bool diag = (tp == tq);

    // phase 0: metadata + bin init
    if (tid < 64) {
      int mp = (tp << 6) + tid;
      int pg = (mp < M) ? list[mp] : -1;
      nodeP[tid] = pg;
      labP[tid]  = (pg >= 0) ? labels[pg] : -1;
      degP[tid]  = (pg >= 0) ? deg[pg] : 0;
      posP[tid]  = (pg >= 0) ? pos[pg] : 0.f;
      selfP[tid] = (pg >= 0) ? (int)((bits[(size_t)pg * NW + (pg >> 6)] >> (pg & 63)) & 1ULL) : 0;
    } else if (tid < 128) {
      int r = tid - 64;
      int mq = (tq << 6) + r;
      int qg = (mq < M) ? list[mq] : -1;
      nodeQ[r] = qg;
      labQ[r]  = (qg >= 0) ? labels[qg] : -1;
      degQ[r]  = (qg >= 0) ? deg[qg] : 0;
      posQ[r]  = (qg >= 0) ? pos[qg] : 0.f;
      selfQ[r] = (qg >= 0) ? (int)((bits[(size_t)qg * NW + (qg >> 6)] >> (qg & 63)) & 1ULL) : 0;
    }
    for (int b = tid; b < 100; b += 256) { binT[b] = 0.f; binS[b] = 0; binI[b] = 0; }
    __syncthreads();

    int acc[4][4];
#pragma unroll
    for (int i = 0; i < 4; i++)
#pragma unroll
      for (int j = 0; j < 4; j++) acc[i][j] = 0;

    for (int c = 0; c < NW / CH; c++) {
      // stage chunk c: pre-swizzled GLOBAL source, linear LDS dest (b128)
#pragma unroll
      for (int k = 0; k < 4; k++) {
        int s  = (k << 8) + tid;     // 0..1023 : 64 rows x 16 16B-units
        int r  = s >> 4;
        int xp = s & 15;
        int lw = xp ^ ((r >> 2) & 7);            // logical 16B-unit index
        int gcol = c * CH + (lw << 1);
        int pg = nodeP[r], qg = nodeQ[r];
        ulonglong2 vp = make_ulonglong2(0ULL, 0ULL);
        ulonglong2 vq = make_ulonglong2(0ULL, 0ULL);
        if (pg >= 0) vp = *(const ulonglong2*)(bits + (size_t)pg * NW + gcol);
        if (qg >= 0) vq = *(const ulonglong2*)(bits + (size_t)qg * NW + gcol);
        *(ulonglong2*)&BPs[r][xp << 1] = vp;
        *(ulonglong2*)&BQs[r][xp << 1] = vq;
      }
      __syncthreads();
#pragma unroll 4
      for (int w = 0; w < CH; w++) {
        u64 rp[4], rq[4];
#pragma unroll
        for (int i = 0; i < 4; i++) rp[i] = BPs[(ty << 2) + i][w ^ swzP];
#pragma unroll
        for (int j = 0; j < 4; j++) rq[j] = BQs[(tx << 2) + j][w ^ swzQ];
#pragma unroll
        for (int i = 0; i < 4; i++)
#pragma unroll
          for (int j = 0; j < 4; j++)
            acc[i][j] += (int)__popcll(rp[i] & rq[j]);
      }
      __syncthreads();
    }

    // epilogue: both orientations per computed pair; adj bits from L2
#pragma unroll
    for (int i = 0; i < 4; i++) {
      int pl = (ty << 2) + i;
      int pg = nodeP[pl];
      if (pg < 0) continue;
      int li = labP[pl];
      int dgp = degP[pl];
      int sp = selfP[pl];
      float pp = posP[pl];
#pragma unroll
      for (int j = 0; j < 4; j++) {
        int ql = (tx << 2) + j;
        int qg = nodeQ[ql];
        if (qg < 0) continue;
        int lj = labQ[ql];
        if (li == lj) continue;                 // only off-diag bins matter
        if (diag && pl >= ql) continue;         // unordered once on diag tiles
        int inter = acc[i][j];
        u64 rwp = bits[(size_t)pg * NW + (qg >> 6)];
        u64 rwq = bits[(size_t)qg * NW + (pg >> 6)];
        int apq = (int)((rwp >> (qg & 63)) & 1ULL);
        int aqp = (int)((rwq >> (pg & 63)) & 1ULL);
        int sub_f = dgp - inter - (apq & (selfQ[ql] ^ 1));
        int sub_r = degQ[ql] - inter - (aqp & (sp ^ 1));
        float rden = 1.f / (1.f + S1F * (float)inter);
        float xf = (1.f + S1F * (float)sub_f) * rden;
        float xr = (1.f + S1F * (float)sub_r) * rden;
        float Ef = __expf(preds[qg * NC + li] - pp);
        float Er = __expf(preds[pg * NC + lj] - posQ[ql]);
        float vf = 1.f / (1.f + __expf(xf));    // 1 - sigmoid(x)
        float vr = 1.f / (1.f + __expf(xr));
        atomicAdd(&binT[li * NC + lj], Ef * vf);
        atomicAdd(&binT[lj * NC + li], Er * vr);
        if (sub_f > 0) binS[li * NC + lj] = 1;  // same-value stores: safe
        if (sub_r > 0) binS[lj * NC + li] = 1;
        if (inter > 0) { binI[li * NC + lj] = 1; binI[lj * NC + li] = 1; }
      }
    }
    __syncthreads();

    // flush tile bins
    for (int b = tid; b < 100; b += 256) {
      float v = binT[b];
      if (v != 0.f) atomicAdd(&gT[b], v);
      if (binS[b]) atomicOr(&gS[b], 1);
      if (binI[b]) atomicOr(&gI[b], 1);
    }
    __syncthreads();   // protect LDS before next tile
  }
}

// ---------------- kernel 5: final gate + reduce ----------------------------
__global__ __launch_bounds__(128) void finalize_kernel(
    const float* __restrict__ gT, const int* __restrict__ gS,
    const int* __restrict__ gI, const int* __restrict__ Ncnt,
    const float* __restrict__ ceAcc, float* __restrict__ out) {
  __shared__ float red[128];
  int tid = threadIdx.x;
  float val = 0.f;
  if (tid < 100) {
    int i = tid / NC, j = tid - (tid / NC) * NC;
    if (i != j && gS[tid] != 0 && gI[tid] != 0) {
      float Ni = fmaxf((float)Ncnt[i], 1.f);
      float Nj = fmaxf((float)Ncnt[j], 1.f);
      val = gT[tid] / (Ni * Nj);
    }
  }
  red[tid] = val;
  __syncthreads();
  for (int s = 64; s > 0; s >>= 1) {
    if (tid < s) red[tid] += red[tid + s];
    __syncthreads();
  }
  if (tid == 0) out[0] = ceAcc[0] / (float)NN + 0.001f * red[0];
}

// ---------------- launch ---------------------------------------------------
extern "C" void kernel_launch(void* const* d_in, const int* in_sizes, int n_in,
                              void* d_out, int out_size, void* d_ws, size_t ws_size,
                              hipStream_t stream) {
  const float* preds  = (const float*)d_in[0];
  const int*   labels = (const int*)d_in[1];
  const int*   mask   = (const int*)d_in[2];
  const int*   adj    = (const int*)d_in[3];

  char* ws = (char*)d_ws;
  // workspace layout (bytes):
  //   [0, 2097152)        bits   (4096 rows x 64 u64)
  //   [2097152, +16384)   deg    (int[4096])
  //   [2113536, +16384)   pos    (float[4096])
  //   [2129920, +16384)   list   (int[4096])
  //   [2146304, +1536)    accumulators (zeroed each call)
  u64*   bits  = (u64*)(ws + 0);
  int*   deg   = (int*)(ws + 2097152);
  float* pos   = (float*)(ws + 2113536);
  int*   list  = (int*)(ws + 2129920);
  char*  accb  = ws + 2146304;
  float* ceAcc = (float*)(accb + 0);
  int*   Mcnt  = (int*)(accb + 8);
  int*   Ncnt  = (int*)(accb + 16);      // 10 ints
  float* gT    = (float*)(accb + 64);    // 100 floats
  int*   gS    = (int*)(accb + 512);     // 100 ints (flags)
  int*   gI    = (int*)(accb + 1024);    // 100 ints (flags)

  hipMemsetAsync(accb, 0, 1536, stream);

  hipLaunchKernelGGL(pack_bits_kernel, dim3(NN), dim3(256), 0, stream, adj, bits, deg);
  hipLaunchKernelGGL(node_kernel, dim3(NN / 256), dim3(256), 0, stream,
                     preds, labels, mask, pos, Ncnt, ceAcc);
  hipLaunchKernelGGL(compact_kernel, dim3(1), dim3(256), 0, stream, mask, list, Mcnt);
  // max tiles = 64*65/2 = 2080 (grid-stride guards the actual count)
  hipLaunchKernelGGL(pair_kernel, dim3(2080), dim3(256), 0, stream,
                     bits, deg, pos, preds, labels, list, Mcnt, gT, gS, gI);
  hipLaunchKernelGGL(finalize_kernel, dim3(1), dim3(128), 0, stream,
                     gT, gS, gI, Ncnt, ceAcc, (float*)d_out);
}

// Round 5
// 103.985 us; speedup vs baseline: 1.5295x; 1.0813x over previous
//
#include <hip/hip_runtime.h>

#define NN 4096
#define NC 10
#define NW 64            // u64 words per adjacency row
#define CHW 16           // words per staged chunk
#define NCHUNK 4         // NW / CHW
typedef unsigned long long u64;

#define S1F 0.73105857863000489f   // sigmoid(1.0)

// ---------------- kernel 1: pack adjacency rows into bitmasks + degrees ----
__global__ __launch_bounds__(256) void pack_bits_kernel(
    const int* __restrict__ adj, u64* __restrict__ bits, int* __restrict__ deg) {
  int p = blockIdx.x;
  int tid = threadIdx.x;
  int wv = tid >> 6, lane = tid & 63;
  const int* row = adj + (size_t)p * NN;
  int cnt = 0;
  for (int w = wv; w < NW; w += 4) {
    int a = row[(w << 6) + lane];
    u64 b = __ballot(a != 0);
    if (lane == 0) bits[(size_t)p * NW + w] = b;
    cnt += (a != 0) ? 1 : 0;
  }
  __shared__ int red[256];
  red[tid] = cnt;
  __syncthreads();
  for (int s = 128; s > 0; s >>= 1) {
    if (tid < s) red[tid] += red[tid + s];
    __syncthreads();
  }
  if (tid == 0) deg[p] = red[0];
}

// ---------------- kernel 2: per-node CE + pos + per-class masked counts ----
__global__ __launch_bounds__(256) void node_kernel(
    const float* __restrict__ preds, const int* __restrict__ labels,
    const int* __restrict__ mask, float* __restrict__ pos,
    int* __restrict__ Ncnt, float* __restrict__ ceAcc) {
  int n = blockIdx.x * blockDim.x + threadIdx.x;
  float ce = 0.f;
  if (n < NN) {
    int l = labels[n];
    float r[NC];
    float mx = -1e30f, rl = 0.f;
#pragma unroll
    for (int c = 0; c < NC; c++) {
      float v = preds[n * NC + c];
      r[c] = v;
      if (c == l) rl = v;
      mx = fmaxf(mx, v);
    }
    float s = 0.f;
#pragma unroll
    for (int c = 0; c < NC; c++) s += expf(r[c] - mx);
    float lse = mx + logf(s);
    pos[n] = rl;
    ce = lse - rl;
    if (mask[n] != 0) atomicAdd(&Ncnt[l], 1);
  }
  __shared__ float red[256];
  red[threadIdx.x] = ce;
  __syncthreads();
  for (int s = 128; s > 0; s >>= 1) {
    if (threadIdx.x < s) red[threadIdx.x] += red[threadIdx.x + s];
    __syncthreads();
  }
  if (threadIdx.x == 0) atomicAdd(ceAcc, red[0]);
}

// ---------------- kernel 3: deterministic mask compaction (1 block) --------
__global__ __launch_bounds__(256) void compact_kernel(
    const int* __restrict__ mask, int* __restrict__ list, int* __restrict__ Mcount) {
  __shared__ int cnt[256];
  int tid = threadIdx.x;
  int base = tid * 16;
  int c = 0;
  for (int i = 0; i < 16; i++) c += (mask[base + i] != 0) ? 1 : 0;
  cnt[tid] = c;
  __syncthreads();
  for (int s = 1; s < 256; s <<= 1) {
    int v = (tid >= s) ? cnt[tid - s] : 0;
    __syncthreads();
    cnt[tid] += v;
    __syncthreads();
  }
  int off = cnt[tid] - c;
  for (int i = 0; i < 16; i++) {
    int idx = base + i;
    if (mask[idx] != 0) list[off++] = idx;
  }
  if (tid == 255) *Mcount = cnt[255];
}

// ---------------- kernel 4: wave-autonomous 32x32 pair tiles ---------------
// Each WAVE owns one 32x32 masked-pair tile (tp<=tq over 32-bands). No
// __syncthreads in the main loop: per-wave LDS slice, wave-synchronous DS
// (in-order per wave) + lgkmcnt. Chunked staging (16 words) with register
// prefetch of the next chunk under the current popc loop. 16B slots
// swizzled slot^=(row>>2)&7 -> ds_read_b128 is 8-addr broadcast,
// conflict-free, and word pairs stay in logical order (bit0 untouched).
__global__ __launch_bounds__(256, 2) void pair_kernel(
    const u64* __restrict__ bits, const int* __restrict__ deg,
    const float* __restrict__ pos, const float* __restrict__ preds,
    const int* __restrict__ labels, const int* __restrict__ list,
    const int* __restrict__ Mcount,
    float* __restrict__ gT, int* __restrict__ gS, int* __restrict__ gI) {
  __shared__ __align__(16) u64 TB[4][64][CHW];   // 32 KB: 4 waves x 64 rows x 16 words
  __shared__ int mNode[4][64], mLab[4][64], mDeg[4][64], mSelf[4][64];
  __shared__ float mPos[4][64];
  __shared__ float binT[100];
  __shared__ int fS[100], fI[100];

  int tid = threadIdx.x;
  int wv = tid >> 6, lane = tid & 63;
  for (int b = tid; b < 100; b += 256) { binT[b] = 0.f; fS[b] = 0; fI[b] = 0; }
  __syncthreads();                                // bins ready (barrier #1)

  int M = *Mcount;
  int ntp = (M + 31) >> 5;
  int ntiles = (ntp * (ntp + 1)) >> 1;
  int gw = blockIdx.x * 4 + wv;
  int nw = gridDim.x * 4;

  int lp = lane >> 3, lq = lane & 7;              // 8x8 lane grid, 4x4 pairs each
  int rowHash = (lane >> 2) & 7;                  // staging swizzle for row=lane
  u64 (*tb)[CHW] = TB[wv];

  for (int t = gw; t < ntiles; t += nw) {
    int tp = 0, rem = t;
    while (rem >= ntp - tp) { rem -= ntp - tp; tp++; }
    int tq = tp + rem;
    bool diag = (tp == tq);

    // ---- per-row metadata (lane owns row `lane`: 0-31 = P, 32-63 = Q)
    int mi = (lane < 32) ? (tp * 32 + lane) : (tq * 32 + (lane - 32));
    int nd = (mi < M) ? list[mi] : -1;
    int lb = -1, dg = 0, sf = 0;
    float ps = 0.f;
    if (nd >= 0) {
      lb = labels[nd];
      dg = deg[nd];
      ps = pos[nd];
      sf = (int)((bits[(size_t)nd * NW + (nd >> 6)] >> (nd & 63)) & 1ULL);
    }
    mNode[wv][lane] = nd; mLab[wv][lane] = lb; mDeg[wv][lane] = dg;
    mSelf[wv][lane] = sf; mPos[wv][lane] = ps;

    const u64* rowp = bits + (size_t)((nd >= 0) ? nd : 0) * NW;
    bool live = (nd >= 0);

    int acc[4][4];
#pragma unroll
    for (int i = 0; i < 4; i++)
#pragma unroll
      for (int j = 0; j < 4; j++) acc[i][j] = 0;

    // prefetch chunk 0 (8 x 16B per lane)
    ulonglong2 pf[8];
#pragma unroll
    for (int x = 0; x < 8; x++)
      pf[x] = live ? *(const ulonglong2*)(rowp + (x << 1))
                   : make_ulonglong2(0ULL, 0ULL);

    for (int c = 0; c < NCHUNK; c++) {
      // write staged regs to this wave's LDS slice (swizzled 16B slots)
#pragma unroll
      for (int x = 0; x < 8; x++)
        *(ulonglong2*)&tb[lane][(x ^ rowHash) << 1] = pf[x];
      // issue next chunk's global loads (in flight under compute)
      if (c < NCHUNK - 1) {
        const u64* src = rowp + ((c + 1) * CHW);
#pragma unroll
        for (int x = 0; x < 8; x++)
          pf[x] = live ? *(const ulonglong2*)(src + (x << 1))
                       : make_ulonglong2(0ULL, 0ULL);
      }
      // wave-synchronous: drain DS writes before reads (no barrier)
      asm volatile("s_waitcnt lgkmcnt(0)" ::: "memory");

#pragma unroll
      for (int y = 0; y < 8; y++) {               // 8 word-pairs per chunk
        ulonglong2 RP[4], RQ[4];
#pragma unroll
        for (int i = 0; i < 4; i++)
          RP[i] = *(ulonglong2*)&tb[(lp << 2) + i][(y ^ lp) << 1];
#pragma unroll
        for (int j = 0; j < 4; j++)
          RQ[j] = *(ulonglong2*)&tb[32 + (lq << 2) + j][(y ^ lq) << 1];
#pragma unroll
        for (int i = 0; i < 4; i++)
#pragma unroll
          for (int j = 0; j < 4; j++)
            acc[i][j] += (int)__popcll(RP[i].x & RQ[j].x)
                       + (int)__popcll(RP[i].y & RQ[j].y);
      }
    }

    // ---- epilogue: both orientations per unordered pair
#pragma unroll
    for (int i = 0; i < 4; i++) {
      int pl = (lp << 2) + i;
      int pg = mNode[wv][pl];
      if (pg < 0) continue;
      int li  = mLab[wv][pl];
      int dgp = mDeg[wv][pl];
      int sp  = mSelf[wv][pl];
      float pp = mPos[wv][pl];
#pragma unroll
      for (int j = 0; j < 4; j++) {
        int qr = (lq << 2) + j;                   // Q row 0..31
        int qg = mNode[wv][32 + qr];
        if (qg < 0) continue;
        int lj = mLab[wv][32 + qr];
        if (li == lj) continue;                   // only off-diag bins matter
        if (diag && pl >= qr) continue;           // unordered once on diag tiles
        int inter = acc[i][j];
        u64 rwp = bits[(size_t)pg * NW + (qg >> 6)];
        u64 rwq = bits[(size_t)qg * NW + (pg >> 6)];
        int apq = (int)((rwp >> (qg & 63)) & 1ULL);
        int aqp = (int)((rwq >> (pg & 63)) & 1ULL);
        int sq  = mSelf[wv][32 + qr];
        int sub_f = dgp - inter - (apq & (sq ^ 1));
        int sub_r = mDeg[wv][32 + qr] - inter - (aqp & (sp ^ 1));
        float rden = 1.f / (1.f + S1F * (float)inter);
        float xf = (1.f + S1F * (float)sub_f) * rden;
        float xr = (1.f + S1F * (float)sub_r) * rden;
        float Ef = __expf(preds[qg * NC + li] - pp);
        float Er = __expf(preds[pg * NC + lj] - mPos[wv][32 + qr]);
        float vf = 1.f / (1.f + __expf(xf));      // 1 - sigmoid(x)
        float vr = 1.f / (1.f + __expf(xr));
        atomicAdd(&binT[li * NC + lj], Ef * vf);
        atomicAdd(&binT[lj * NC + li], Er * vr);
        if (sub_f > 0) fS[li * NC + lj] = 1;      // same-value stores: safe
        if (sub_r > 0) fS[lj * NC + li] = 1;
        if (inter > 0) { fI[li * NC + lj] = 1; fI[lj * NC + li] = 1; }
      }
    }
    // next tile: DS in-order per wave makes meta/TB rewrite safe, no barrier
  }

  __syncthreads();                                // all waves done (barrier #2)
  for (int b = tid; b < 100; b += 256) {
    float v = binT[b];
    if (v != 0.f) atomicAdd(&gT[b], v);
    if (fS[b]) atomicOr(&gS[b], 1);
    if (fI[b]) atomicOr(&gI[b], 1);
  }
}

// ---------------- kernel 5: final gate + reduce ----------------------------
__global__ __launch_bounds__(128) void finalize_kernel(
    const float* __restrict__ gT, const int* __restrict__ gS,
    const int* __restrict__ gI, const int* __restrict__ Ncnt,
    const float* __restrict__ ceAcc, float* __restrict__ out) {
  __shared__ float red[128];
  int tid = threadIdx.x;
  float val = 0.f;
  if (tid < 100) {
    int i = tid / NC, j = tid - (tid / NC) * NC;
    if (i != j && gS[tid] != 0 && gI[tid] != 0) {
      float Ni = fmaxf((float)Ncnt[i], 1.f);
      float Nj = fmaxf((float)Ncnt[j], 1.f);
      val = gT[tid] / (Ni * Nj);
    }
  }
  red[tid] = val;
  __syncthreads();
  for (int s = 64; s > 0; s >>= 1) {
    if (tid < s) red[tid] += red[tid + s];
    __syncthreads();
  }
  if (tid == 0) out[0] = ceAcc[0] / (float)NN + 0.001f * red[0];
}

// ---------------- launch ---------------------------------------------------
extern "C" void kernel_launch(void* const* d_in, const int* in_sizes, int n_in,
                              void* d_out, int out_size, void* d_ws, size_t ws_size,
                              hipStream_t stream) {
  const float* preds  = (const float*)d_in[0];
  const int*   labels = (const int*)d_in[1];
  const int*   mask   = (const int*)d_in[2];
  const int*   adj    = (const int*)d_in[3];

  char* ws = (char*)d_ws;
  u64*   bits  = (u64*)(ws + 0);
  int*   deg   = (int*)(ws + 2097152);
  float* pos   = (float*)(ws + 2113536);
  int*   list  = (int*)(ws + 2129920);
  char*  accb  = ws + 2146304;
  float* ceAcc = (float*)(accb + 0);
  int*   Mcnt  = (int*)(accb + 8);
  int*   Ncnt  = (int*)(accb + 16);      // 10 ints
  float* gT    = (float*)(accb + 64);    // 100 floats
  int*   gS    = (int*)(accb + 512);     // 100 ints (flags)
  int*   gI    = (int*)(accb + 1024);    // 100 ints (flags)

  hipMemsetAsync(accb, 0, 1536, stream);

  hipLaunchKernelGGL(pack_bits_kernel, dim3(NN), dim3(256), 0, stream, adj, bits, deg);
  hipLaunchKernelGGL(node_kernel, dim3(NN / 256), dim3(256), 0, stream,
                     preds, labels, mask, pos, Ncnt, ceAcc);
  hipLaunchKernelGGL(compact_kernel, dim3(1), dim3(256), 0, stream, mask, list, Mcnt);
  // worst case M=4096: ntp=128 bands -> 8256 wave-tiles; 2080 blocks x 4
  // waves = 8320 waves covers it (wave-stride loop guards the rest)
  hipLaunchKernelGGL(pair_kernel, dim3(2080), dim3(256), 0, stream,
                     bits, deg, pos, preds, labels, list, Mcnt, gT, gS, gI);
  hipLaunchKernelGGL(finalize_kernel, dim3(1), dim3(128), 0, stream,
                     gT, gS, gI, Ncnt, ceAcc, (float*)d_out);
}